// Round 2
// baseline (10279.171 us; speedup 1.0000x reference)
//
#include <hip/hip_runtime.h>
#include <cmath>

// Scattering transform, two orders. Both stages are the same fused op.
// Per block: (batch b, input channel gq, 32x32 output tile).
//   - phi conv stride 2            -> out channel gq
//   - 8x (psi_r,psi_i) conv stride 2, modulus, phi-smooth stride 1
//                                  -> out channels Cin + gq*8 + j
// Stage 1: x  [32][ 3][512][512] -> s1  [32][ 27][256][256] (workspace)
// Stage 2: s1 [32][27][256][256] -> out [32][243][128][128]
//
// Design: 4-wide register blocking, all LDS reads as aligned float4
// (ds_read_b128), weights staged in LDS (broadcast reads, no s_load spam).

#define TILE  32
#define XSTR  84      // xs row stride (floats), multiple of 4
#define XROWS 82      // 81 needed + 1 guard row for the last b128 window
#define XCOLS 83      // valid columns (logical input cols ix0..ix0+82)
#define UROWS 38
#define USTR  40
#define NGRP  380     // 38 u-rows * 10 col-groups (4-wide)

__global__ void pack_weights_kernel(const float* __restrict__ psi_r,
                                    const float* __restrict__ psi_i,
                                    float* __restrict__ wpack) {
  // wpack: [g=3][half=2][tap=49][jh=4][ri=2]
  int idx = blockIdx.x * 256 + threadIdx.x;
  if (idx >= 2352) return;
  int ri   = idx & 1;
  int jh   = (idx >> 1) & 3;
  int tap  = (idx >> 3) % 49;
  int half = (idx / 392) & 1;
  int g    = idx / 784;
  int src  = (g * 8 + half * 4 + jh) * 49 + tap;
  wpack[idx] = ri ? psi_i[src] : psi_r[src];
}

__global__ __launch_bounds__(256, 3) void scatter_stage_kernel(
    const float* __restrict__ in,     // [B][Cin][Hin][Win]
    const float* __restrict__ phi,    // [3][49]
    const float* __restrict__ wpack,  // [3][2][49][4][2]
    float* __restrict__ out,          // [B][Cin*9][Hin/2][Win/2]
    int Cin, int Hin, int Win, int tilesX)
{
  __shared__ __align__(16) float xs[XROWS][XSTR];   // 27552 B
  __shared__ __align__(16) float us[4][UROWS][USTR];// 24320 B
  __shared__ __align__(16) float wpsi[49 * 8];      //  1568 B
  __shared__ __align__(16) float wphi[3][7][8];     //   672 B  -> 54112 B total

  const int Hout = Hin >> 1, Wout = Win >> 1;
  const int gq  = blockIdx.y;
  const int b   = blockIdx.z;
  const int ty0 = (blockIdx.x / tilesX) * TILE;
  const int tx0 = (blockIdx.x % tilesX) * TILE;
  const int g3  = gq % 3;
  const int tid = threadIdx.x;
  const int tc  = tid & 7;    // thread-col: 4-wide output group
  const int ty  = tid >> 3;   // output row 0..31

  const float* __restrict__ inp =
      in + ((size_t)b * Cin + gq) * (size_t)(Hin * Win);
  float* __restrict__ outp =
      out + (size_t)b * (size_t)(Cin * 9) * (size_t)(Hout * Wout);

  // ---- stage weights into LDS ----
  if (tid < 168) {
    int p = tid / 56, r = (tid / 8) % 7, kx = tid & 7;
    wphi[p][r][kx] = (kx < 7) ? phi[p * 49 + r * 7 + kx] : 0.f;
  }
  {
    const float* __restrict__ wsrc = wpack + (g3 * 2 + 0) * 392;
    for (int i = tid; i < 392; i += 256) wpsi[i] = wsrc[i];
  }

  // ---- load input tile (zero-padded), full stride zero-filled ----
  const int iy0 = 2 * ty0 - 9;
  const int ix0 = 2 * tx0 - 11;   // shifted so psi windows start 16B-aligned
  for (int i = tid; i < XROWS * XSTR; i += 256) {
    int r = i / XSTR, c = i - r * XSTR;
    int gy = iy0 + r, gx = ix0 + c;
    float v = 0.0f;
    if (c < XCOLS && (unsigned)gy < (unsigned)Hin && (unsigned)gx < (unsigned)Win)
      v = inp[(size_t)gy * Win + gx];
    xs[r][c] = v;
  }
  __syncthreads();

  // ---- phi low-pass, stride 2 -> out channel gq ----
  // output (ty0+ty, tx0+4*tc+o); input col = 8tc+8 + 2o+kx (window base 8tc+8)
  {
    float a0 = 0, a1 = 0, a2 = 0, a3 = 0;
    #pragma unroll
    for (int ky = 0; ky < 7; ky++) {
      const float4* xr = (const float4*)&xs[2 * ty + 6 + ky][8 * tc + 8];
      float4 q0 = xr[0], q1 = xr[1], q2 = xr[2], q3 = xr[3];
      float xw[16] = {q0.x, q0.y, q0.z, q0.w, q1.x, q1.y, q1.z, q1.w,
                      q2.x, q2.y, q2.z, q2.w, q3.x, q3.y, q3.z, q3.w};
      #pragma unroll
      for (int kx = 0; kx < 7; kx++) {
        float wv = wphi[g3][ky][kx];
        a0 = fmaf(xw[0 + kx], wv, a0);
        a1 = fmaf(xw[2 + kx], wv, a1);
        a2 = fmaf(xw[4 + kx], wv, a2);
        a3 = fmaf(xw[6 + kx], wv, a3);
      }
    }
    float4 res = {a0, a1, a2, a3};
    *(float4*)&outp[((size_t)gq * Hout + (ty0 + ty)) * Wout + tx0 + 4 * tc] = res;
  }

  // ---- band-pass modulus + smoothing, 4 psi filters per half ----
  #pragma unroll 1
  for (int half = 0; half < 2; half++) {
    // psi conv stride 2 over u-halo tile: u rows r=0..37 (logical oy-3..oy+34),
    // col groups gc=0..9 (logical ox-4..ox+35, 4-wide)
    for (int gi = tid; gi < NGRP; gi += 256) {
      int r  = gi / 10;
      int gc = gi - r * 10;
      float acc[4][8];
      #pragma unroll
      for (int o = 0; o < 4; o++)
        #pragma unroll
        for (int k = 0; k < 8; k++) acc[o][k] = 0.f;

      #pragma unroll
      for (int ky = 0; ky < 7; ky++) {
        const float4* xr = (const float4*)&xs[2 * r + ky][8 * gc];
        float4 q0 = xr[0], q1 = xr[1], q2 = xr[2], q3 = xr[3];
        float xw[16] = {q0.x, q0.y, q0.z, q0.w, q1.x, q1.y, q1.z, q1.w,
                        q2.x, q2.y, q2.z, q2.w, q3.x, q3.y, q3.z, q3.w};
        #pragma unroll
        for (int kx = 0; kx < 7; kx++) {
          const float4* wv = (const float4*)&wpsi[(ky * 7 + kx) * 8];
          float4 wa = wv[0], wb = wv[1];
          #pragma unroll
          for (int o = 0; o < 4; o++) {
            float xv = xw[2 * o + kx];
            acc[o][0] = fmaf(xv, wa.x, acc[o][0]);
            acc[o][1] = fmaf(xv, wa.y, acc[o][1]);
            acc[o][2] = fmaf(xv, wa.z, acc[o][2]);
            acc[o][3] = fmaf(xv, wa.w, acc[o][3]);
            acc[o][4] = fmaf(xv, wb.x, acc[o][4]);
            acc[o][5] = fmaf(xv, wb.y, acc[o][5]);
            acc[o][6] = fmaf(xv, wb.z, acc[o][6]);
            acc[o][7] = fmaf(xv, wb.w, acc[o][7]);
          }
        }
      }
      // modulus + validity (positions outside the stride-2 output grid are 0)
      int uy_g = ty0 + r - 3;
      int ux_g = tx0 - 4 + 4 * gc;
      bool vy = (unsigned)uy_g < (unsigned)Hout;
      #pragma unroll
      for (int f = 0; f < 4; f++) {
        float sv[4];
        #pragma unroll
        for (int o = 0; o < 4; o++) {
          bool v = vy && ((unsigned)(ux_g + o) < (unsigned)Wout);
          float rr = acc[o][2 * f], ii = acc[o][2 * f + 1];
          sv[o] = v ? sqrtf(rr * rr + ii * ii) : 0.f;
        }
        float4 pack = {sv[0], sv[1], sv[2], sv[3]};
        *(float4*)&us[f][r][4 * gc] = pack;
      }
    }
    __syncthreads();   // us visible; psi reads of wpsi done

    if (half == 0) {   // stage next half's psi weights (overlaps smoothing)
      const float* __restrict__ wsrc = wpack + (g3 * 2 + 1) * 392;
      for (int i = tid; i < 392; i += 256) wpsi[i] = wsrc[i];
    }

    // smoothing: depthwise phi stride 1 on us -> out channels Cin+gq*8+half*4+j4
    #pragma unroll
    for (int j4 = 0; j4 < 4; j4++) {
      int jj = half * 4 + j4;
      int pf = (gq * 8 + jj) % 3;
      float a0 = 0, a1 = 0, a2 = 0, a3 = 0;
      #pragma unroll
      for (int ky = 0; ky < 7; ky++) {
        const float4* ur = (const float4*)&us[j4][ty + ky][4 * tc];
        float4 q0 = ur[0], q1 = ur[1], q2 = ur[2];
        float uw[12] = {q0.x, q0.y, q0.z, q0.w, q1.x, q1.y,
                        q1.z, q1.w, q2.x, q2.y, q2.z, q2.w};
        #pragma unroll
        for (int kx = 0; kx < 7; kx++) {
          float wv = wphi[pf][ky][kx];
          a0 = fmaf(uw[1 + kx], wv, a0);
          a1 = fmaf(uw[2 + kx], wv, a1);
          a2 = fmaf(uw[3 + kx], wv, a2);
          a3 = fmaf(uw[4 + kx], wv, a3);
        }
      }
      float4 res = {a0, a1, a2, a3};
      *(float4*)&outp[((size_t)(Cin + gq * 8 + jj) * Hout + (ty0 + ty)) * Wout +
                      tx0 + 4 * tc] = res;
    }
    if (half == 0) __syncthreads();  // us free + wpsi(half1) ready
  }
}

extern "C" void kernel_launch(void* const* d_in, const int* in_sizes, int n_in,
                              void* d_out, int out_size, void* d_ws, size_t ws_size,
                              hipStream_t stream) {
  const float* x     = (const float*)d_in[0];  // [32][3][512][512]
  const float* phi   = (const float*)d_in[1];  // [3][1][7][7]
  const float* psi_r = (const float*)d_in[2];  // [24][1][7][7]
  const float* psi_i = (const float*)d_in[3];  // [24][1][7][7]
  float* out = (float*)d_out;                  // [32][243][128][128]

  float* s1    = (float*)d_ws;                           // [32][27][256][256]
  float* wpack = s1 + (size_t)32 * 27 * 256 * 256;       // 2352 floats

  pack_weights_kernel<<<dim3(10), 256, 0, stream>>>(psi_r, psi_i, wpack);

  // Stage 1: x -> s1   (Cin=3, 512x512 -> 256x256; 8x8 tiles)
  scatter_stage_kernel<<<dim3(64, 3, 32), 256, 0, stream>>>(
      x, phi, wpack, s1, 3, 512, 512, 8);

  // Stage 2: s1 -> out (Cin=27, 256x256 -> 128x128; 4x4 tiles)
  scatter_stage_kernel<<<dim3(16, 27, 32), 256, 0, stream>>>(
      s1, phi, wpack, out, 27, 256, 256, 4);
}